// Round 2
// baseline (154.045 us; speedup 1.0000x reference)
//
#include <hip/hip_runtime.h>
#include <cmath>

#define E_ 4
#define L_ 10
#define M_ 512
#define F_ 128
#define S_ 1000

typedef unsigned int u32;
typedef _Float16 f16;
typedef __attribute__((ext_vector_type(8))) _Float16 v8h;
typedef __attribute__((ext_vector_type(4))) float v4f;

__device__ __forceinline__ float fexp2(float a){
#if __has_builtin(__builtin_amdgcn_exp2f)
  return __builtin_amdgcn_exp2f(a);
#else
  return exp2f(a);
#endif
}

// ws float layout (total 282640 <= 288768 proven available):
// [0..4)         splat consts: posScale, posOff, stepFS, leftS (written by k_red)
// [8]            hscale (written by k_red, read by k_fin)
// [16..1296)     per-gemm-block min   (unique slot per block, no init needed)
// [1296..2576)   per-gemm-block max
// [2576..7696)   std S1 partials [40][128]
// [7696..12816)  std S2 partials [40][128]
// [12816..20496) dpair[6][1280]
// [20496..282640) projT[E][L][F][M] (unscaled, m contiguous)

// blocks 0..1279: MFMA f16 GEMM tile (direct global loads/stores) + block min/max
// blocks 1280..1319: per-(e,l) std partial sums
__global__ __launch_bounds__(256) void k_pre(const float* __restrict__ mat,
                       const float* __restrict__ par,
                       float* __restrict__ projT, float* __restrict__ wsf){
  __shared__ float sm[512];
  int b = blockIdx.x, tid = threadIdx.x;
  if (b >= 1280){
    int el = b - 1280;
    int f = tid & 127, part = tid >> 7;
    const float* base = mat + ((size_t)el * M_ + part*256) * F_;
    float s = 0.f, s2 = 0.f;
    for (int i = 0; i < 256; i++){
      float v = base[i*F_ + f];
      s += v; s2 += v*v;
    }
    sm[tid] = s; sm[256 + tid] = s2;
    __syncthreads();
    if (tid < 128){
      wsf[2576 + el*128 + tid] = sm[tid] + sm[tid+128];
      wsf[7696 + el*128 + tid] = sm[256+tid] + sm[256+tid+128];
    }
    return;
  }
  int el = b >> 5, mt = (b & 31) * 16;
  int lane = tid & 63, wave = tid >> 6;
  int q = (lane >> 4) & 3, m16 = lane & 15;
  const float* arow = mat + ((size_t)el * M_ + mt + m16) * F_;
  v4f acc0 = {0.f,0.f,0.f,0.f}, acc1 = {0.f,0.f,0.f,0.f};
  #pragma unroll
  for (int c = 0; c < 4; c++){
    float4 a0 = *(const float4*)&arow[c*32 + q*8];
    float4 a1 = *(const float4*)&arow[c*32 + q*8 + 4];
    v8h af, b0, b1;
    af[0]=(f16)a0.x; af[1]=(f16)a0.y; af[2]=(f16)a0.z; af[3]=(f16)a0.w;
    af[4]=(f16)a1.x; af[5]=(f16)a1.y; af[6]=(f16)a1.z; af[7]=(f16)a1.w;
    const float* pb = par + (c*32 + q*8)*F_ + wave*32 + m16;
    #pragma unroll
    for (int j = 0; j < 8; j++){
      b0[j] = (f16)pb[j*F_];
      b1[j] = (f16)pb[j*F_ + 16];
    }
    acc0 = __builtin_amdgcn_mfma_f32_16x16x32_f16(af, b0, acc0, 0, 0, 0);
    acc1 = __builtin_amdgcn_mfma_f32_16x16x32_f16(af, b1, acc1, 0, 0, 0);
  }
  // direct stores: C/D row=q*4+r (m), col=m16 (n) -> projT[el][n][m]
  *(float4*)(projT + ((size_t)el*F_ + wave*32      + m16)*M_ + mt + q*4)
      = make_float4(acc0[0], acc0[1], acc0[2], acc0[3]);
  *(float4*)(projT + ((size_t)el*F_ + wave*32 + 16 + m16)*M_ + mt + q*4)
      = make_float4(acc1[0], acc1[1], acc1[2], acc1[3]);
  float lmin =  3.4e38f, lmax = -3.4e38f;
  #pragma unroll
  for (int r = 0; r < 4; r++){
    lmin = fminf(lmin, fminf(acc0[r], acc1[r]));
    lmax = fmaxf(lmax, fmaxf(acc0[r], acc1[r]));
  }
  #pragma unroll
  for (int d = 32; d >= 1; d >>= 1){
    lmin = fminf(lmin, __shfl_xor(lmin, d, 64));
    lmax = fmaxf(lmax, __shfl_xor(lmax, d, 64));
  }
  if (lane == 0){ sm[wave] = lmin; sm[8+wave] = lmax; }
  __syncthreads();
  if (tid == 0){
    wsf[16   + b] = fminf(fminf(sm[0], sm[1]), fminf(sm[2], sm[3]));
    wsf[1296 + b] = fmaxf(fmaxf(sm[8], sm[9]), fmaxf(sm[10], sm[11]));
  }
}

// one-block reduction: global min/max over 1280 block slots + sum of 5120 stds
// -> writes splat constants wsf[0..3] and hscale wsf[8]
__global__ __launch_bounds__(1024) void k_red(float* __restrict__ wsf, float divisor){
  __shared__ float rmn[1024], rmx[1024], rs[1024];
  int tid = threadIdx.x;
  float mn = 3.4e38f, mx = -3.4e38f, s = 0.f;
  for (int i = tid; i < 1280; i += 1024){
    mn = fminf(mn, wsf[16   + i]);
    mx = fmaxf(mx, wsf[1296 + i]);
  }
  for (int i = tid; i < 5120; i += 1024){
    float a  = wsf[2576 + i];
    float a2 = wsf[7696 + i];
    float mean = a * (1.0f/512.0f);
    float var  = a2 * (1.0f/512.0f) - mean*mean;
    s += sqrtf(fmaxf(var, 0.0f));
  }
  rmn[tid] = mn; rmx[tid] = mx; rs[tid] = s;
  __syncthreads();
  for (int g = 512; g >= 1; g >>= 1){
    if (tid < g){
      rmn[tid] = fminf(rmn[tid], rmn[tid+g]);
      rmx[tid] = fmaxf(rmx[tid], rmx[tid+g]);
      rs[tid] += rs[tid+g];
    }
    __syncthreads();
  }
  if (tid == 0){
    float rstd   = 5120.0f / rs[0];
    float leftS  = rmn[0] * rstd;
    float rightS = rmx[0] * rstd;
    float stepFS = (rightS - leftS) * (1.0f/999.0f);
    float inv2   = 1.0f / (2.0f * stepFS);
    wsf[0] = rstd * inv2;    // posScale
    wsf[1] = leftS * inv2;   // posOff
    wsf[2] = stepFS;
    wsf[3] = leftS;
    wsf[8] = ((rightS - leftS) * (1.0f/1000.0f)) * 0.5f / divisor;  // hscale
  }
}

// KDE: 512 threads (8 waves). Wave (e,h) = (wave>>1, wave&1) handles half of
// env e's samples (splat) and half of its 256 FIR outputs. Fine grid = 2 rounds.
// smem: p/st [0..2048) | hist [2048..4672) | taps [4672..4816) |
//       corr [4816..5072) | pairwise partials [5072..5136)
__global__ __launch_bounds__(512) void k_kde(const float* __restrict__ projT,
                      const int* __restrict__ dlen, const float* __restrict__ wsf,
                      float* __restrict__ dpair, float k2c){
  __shared__ __align__(16) float smem[5136];
  int b = blockIdx.x;          // 0..1279
  int l = b >> 7, f = b & 127;
  int tid = threadIdx.x, wave = tid >> 6, lane = tid & 63;
  int e = wave >> 1, h = wave & 1;
  // stage p UNSCALED (rstd folded into splat constants): one float4 per thread
  {
    int ee = tid >> 7, mq = tid & 127;
    ((float4*)smem)[tid] =
      ((const float4*)(projT + (((size_t)ee * L_ + l) * F_ + f) * M_))[mq];
  }
  // uniform scalar loads of precomputed constants (L2-hot, no reduction)
  float posScale = wsf[0], posOff = wsf[1], stepFS = wsf[2], leftS = wsf[3];
  // zero hist + build tap/corr tables (overlaps the staging load latency)
  for (int idx = tid; idx < 656; idx += 512)
    ((float4*)(smem + 2048))[idx] = make_float4(0.f,0.f,0.f,0.f);
  float sh = 2.0f * stepFS;
  if (tid < 72){
    int u = tid - 34;
    float d0 = (float)(2*u)   * sh;
    float d1 = (float)(2*u-1) * sh;
    float2 t = (tid < 69) ? make_float2(fexp2(k2c*d0*d0), fexp2(k2c*d1*d1))
                          : make_float2(0.f, 0.f);
    *(float2*)&smem[4672 + 2*tid] = t;
  }
  if (tid < 256){
    float xc = fmaf((float)(tid - 1), 4.0f*stepFS, leftS);
    smem[4816 + tid] = fexp2(k2c * xc * xc);
  }
  __syncthreads();   // #1: p staged, hist zeroed, tables built
  // quadratic (TSC) splat; waves (e,0) and (e,1) share env e's histogram
  {
    float* hf = smem + 2048 + e*656;
    const float4* spw4 = (const float4*)(smem + e*512);
    float4 p0 = spw4[h*64 + lane];
    float pv[4] = {p0.x,p0.y,p0.z,p0.w};
    #pragma unroll
    for (int i = 0; i < 4; i++){
      float pos = fmaf(pv[i], posScale, -posOff);
      float n = floorf(pos + 0.5f);
      float d = pos - n;
      float wm = 0.5f*(0.5f-d)*(0.5f-d);
      float wp = 0.5f*(0.5f+d)*(0.5f+d);
      float w0 = 0.75f - d*d;
      int base = (int)n + 71;
      atomicAdd(&hf[base  ], wm);
      atomicAdd(&hf[base+1], w0);
      atomicAdd(&hf[base+2], wp);
    }
  }
  __syncthreads();   // #2: histograms complete, p reads done
  // FIR conv: wave (e,h) computes outputs h*128+lane and h*128+lane+64 of env e
  float lenE = (float)dlen[e*L_ + l];
  float rlen = 1.0f / lenE;
  float padc = 512.0f - lenE;
  {
    const float* sK = smem + 4672;
    const float* hb = smem + 2048 + e*656;
    int o0 = h*128 + lane;
    float a0=0.f, a1=0.f;
    #pragma unroll 8
    for (int uu = 0; uu < 72; uu++){
      float2 kv = *(const float2*)&sK[2*uu];
      int off = 2*(69 - uu) + 2*o0;          // may reach -4 for uu>69: tap=0
      float2 h0 = *(const float2*)&hb[off];
      float2 h1 = *(const float2*)&hb[off + 128];
      a0 = fmaf(h0.x, kv.x, fmaf(h0.y, kv.y, a0));
      a1 = fmaf(h1.x, kv.x, fmaf(h1.y, kv.y, a1));
    }
    const float* sCorr = smem + 4816;
    smem[e*256 + o0     ] = (a0 - padc * sCorr[o0     ]) * rlen;
    smem[e*256 + o0 + 64] = (a1 - padc * sCorr[o0 + 64]) * rlen;
  }
  __syncthreads();   // #3: st complete for all envs
  // fine grid: 4-pt Lagrange cubic on st, then pairwise L1 (2 rounds of 512)
  float ps[6] = {0,0,0,0,0,0};
  #pragma unroll
  for (int r=0;r<2;r++){
    int t = tid + 512*r;
    if (t < S_){
      int cc = t >> 2;
      float u = (float)(t & 3) * 0.25f;
      float um1 = u - 1.0f, um2 = u - 2.0f, up1 = u + 1.0f;
      float w0 = -u * um1 * um2 * (1.0f/6.0f);
      float w1 = up1 * um1 * um2 * 0.5f;
      float w2 = -u * up1 * um2 * 0.5f;
      float w3 = u * up1 * um1 * (1.0f/6.0f);
      float rr[4];
      #pragma unroll
      for (int ee=0;ee<4;ee++){
        const float* st = &smem[ee*256 + cc];
        rr[ee] = w0*st[0] + w1*st[1] + w2*st[2] + w3*st[3];
      }
      ps[0] += fabsf(rr[0]-rr[1]);
      ps[1] += fabsf(rr[0]-rr[2]);
      ps[2] += fabsf(rr[0]-rr[3]);
      ps[3] += fabsf(rr[1]-rr[2]);
      ps[4] += fabsf(rr[1]-rr[3]);
      ps[5] += fabsf(rr[2]-rr[3]);
    }
  }
  #pragma unroll
  for (int pr=0; pr<6; pr++){
    float v = ps[pr];
    #pragma unroll
    for (int d=32; d>=1; d>>=1) v += __shfl_xor(v, d, 64);
    if (lane == 0) smem[5072 + wave*8 + pr] = v;
  }
  __syncthreads();   // #4: partials visible
  if (tid < 6)
    dpair[tid*1280 + b] = smem[5072+tid] + smem[5080+tid] + smem[5088+tid] + smem[5096+tid]
                        + smem[5104+tid] + smem[5112+tid] + smem[5120+tid] + smem[5128+tid];
}

// finalize: scale, masked max over pairs, then max over L + mean over F
__global__ void k_fin(const float* __restrict__ dpair, const float* __restrict__ wsf,
                      const int* __restrict__ istrain, float* __restrict__ out){
  __shared__ float str[1280], ste[1280];
  __shared__ float s1[128], s2[128];
  int tid = threadIdx.x;   // 256 threads, 1 block
  float hscale = wsf[8];
  bool t0 = istrain[0]!=0, t1 = istrain[1]!=0, t2 = istrain[2]!=0, t3 = istrain[3]!=0;
  bool trn[6] = { t0&&t1, t0&&t2, t0&&t3, t1&&t2, t1&&t3, t2&&t3 };
  for (int idx = tid; idx < 1280; idx += 256){
    float tmax = -INFINITY, trmax = -INFINITY;
    #pragma unroll
    for (int pr=0;pr<6;pr++){
      float h = dpair[pr*1280 + idx] * hscale;
      tmax = fmaxf(tmax, h);
      if (trn[pr]) trmax = fmaxf(trmax, h);
    }
    out[idx]        = trmax;   // train_results
    out[1280 + idx] = tmax;    // test_results
    str[idx] = trmax; ste[idx] = tmax;
  }
  __syncthreads();
  if (tid < 128){
    float m1 = -INFINITY, m2 = -INFINITY;
    for (int l=0;l<L_;l++){
      m1 = fmaxf(m1, str[l*F_ + tid]);
      m2 = fmaxf(m2, ste[l*F_ + tid]);
    }
    s1[tid] = m1; s2[tid] = m2;
  }
  __syncthreads();
  for (int g=64; g>=1; g>>=1){
    if (tid < g){ s1[tid] += s1[tid+g]; s2[tid] += s2[tid+g]; }
    __syncthreads();
  }
  if (tid == 0){
    out[2560] = s1[0] * (1.0f/128.0f);
    out[2561] = s2[0] * (1.0f/128.0f);
  }
}

extern "C" void kernel_launch(void* const* d_in, const int* in_sizes, int n_in,
                              void* d_out, int out_size, void* d_ws, size_t ws_size,
                              hipStream_t stream){
  const float* mat = (const float*)d_in[0];
  const float* par = (const float*)d_in[1];
  const int*  dlen = (const int*)d_in[2];
  const int*  istr = (const int*)d_in[3];
  float* out   = (float*)d_out;
  float* wsf   = (float*)d_ws;
  float* dpair = wsf + 12816;
  float* projT = wsf + 20496;

  // host-computable constants (bw's data-dependent factor is identically 1)
  double bw_d   = 1.06 * pow(512.0, -0.2);
  float  bw     = (float)bw_d;
  float  offset = expf(-0.5f / (bw*bw));
  float  k2c    = (float)(log((double)offset) * 1.4426950408889634);  // log2(offset)
  float  divisor = sqrtf(6.283185307179586f) * bw;

  k_pre <<<1320, 256, 0, stream>>>(mat, par, projT, wsf);
  k_red <<<1,   1024, 0, stream>>>(wsf, divisor);
  k_kde <<<1280, 512, 0, stream>>>(projT, dlen, wsf, dpair, k2c);
  k_fin <<<1,    256, 0, stream>>>(dpair, wsf, istr, out);
}

// Round 3
// 143.821 us; speedup vs baseline: 1.0711x; 1.0711x over previous
//
#include <hip/hip_runtime.h>
#include <cmath>

#define E_ 4
#define L_ 10
#define M_ 512
#define F_ 128
#define S_ 1000

typedef unsigned int u32;
typedef _Float16 f16;
typedef __attribute__((ext_vector_type(8))) _Float16 v8h;
typedef __attribute__((ext_vector_type(4))) float v4f;

__device__ __forceinline__ float fexp2(float a){
#if __has_builtin(__builtin_amdgcn_exp2f)
  return __builtin_amdgcn_exp2f(a);
#else
  return exp2f(a);
#endif
}

// ws float layout (total 282640 <= 288768 proven available):
// [0..4)         splat consts: posScale, posOff, stepFS, leftS (written by k_red)
// [8]            hscale (written by k_red, read by k_fin)
// [16..168)      tap table sK2: 76 float2 (zero-padded), written by k_red AFTER
//                the min/max slots are consumed (reuse of the min region)
// [168..424)     corr table [256], written by k_red (reuse of min region)
// [16..1296)     per-gemm-block min   (live only k_pre -> k_red)
// [1296..2576)   per-gemm-block max
// [2576..7696)   std S1 partials [40][128]
// [7696..12816)  std S2 partials [40][128]
// [12816..20496) dpair[6][1280]
// [20496..282640) projT[E][L][F][M] (unscaled, m contiguous)

// blocks 0..1279: MFMA f16 GEMM tile (direct global loads/stores) + block min/max
// blocks 1280..1319: per-(e,l) std partial sums
__global__ __launch_bounds__(256) void k_pre(const float* __restrict__ mat,
                       const float* __restrict__ par,
                       float* __restrict__ projT, float* __restrict__ wsf){
  __shared__ float sm[512];
  int b = blockIdx.x, tid = threadIdx.x;
  if (b >= 1280){
    int el = b - 1280;
    int f = tid & 127, part = tid >> 7;
    const float* base = mat + ((size_t)el * M_ + part*256) * F_;
    float s = 0.f, s2 = 0.f;
    for (int i = 0; i < 256; i++){
      float v = base[i*F_ + f];
      s += v; s2 += v*v;
    }
    sm[tid] = s; sm[256 + tid] = s2;
    __syncthreads();
    if (tid < 128){
      wsf[2576 + el*128 + tid] = sm[tid] + sm[tid+128];
      wsf[7696 + el*128 + tid] = sm[256+tid] + sm[256+tid+128];
    }
    return;
  }
  int el = b >> 5, mt = (b & 31) * 16;
  int lane = tid & 63, wave = tid >> 6;
  int q = (lane >> 4) & 3, m16 = lane & 15;
  const float* arow = mat + ((size_t)el * M_ + mt + m16) * F_;
  v4f acc0 = {0.f,0.f,0.f,0.f}, acc1 = {0.f,0.f,0.f,0.f};
  #pragma unroll
  for (int c = 0; c < 4; c++){
    float4 a0 = *(const float4*)&arow[c*32 + q*8];
    float4 a1 = *(const float4*)&arow[c*32 + q*8 + 4];
    v8h af, b0, b1;
    af[0]=(f16)a0.x; af[1]=(f16)a0.y; af[2]=(f16)a0.z; af[3]=(f16)a0.w;
    af[4]=(f16)a1.x; af[5]=(f16)a1.y; af[6]=(f16)a1.z; af[7]=(f16)a1.w;
    const float* pb = par + (c*32 + q*8)*F_ + wave*32 + m16;
    #pragma unroll
    for (int j = 0; j < 8; j++){
      b0[j] = (f16)pb[j*F_];
      b1[j] = (f16)pb[j*F_ + 16];
    }
    acc0 = __builtin_amdgcn_mfma_f32_16x16x32_f16(af, b0, acc0, 0, 0, 0);
    acc1 = __builtin_amdgcn_mfma_f32_16x16x32_f16(af, b1, acc1, 0, 0, 0);
  }
  // direct stores: C/D row=q*4+r (m), col=m16 (n) -> projT[el][n][m]
  *(float4*)(projT + ((size_t)el*F_ + wave*32      + m16)*M_ + mt + q*4)
      = make_float4(acc0[0], acc0[1], acc0[2], acc0[3]);
  *(float4*)(projT + ((size_t)el*F_ + wave*32 + 16 + m16)*M_ + mt + q*4)
      = make_float4(acc1[0], acc1[1], acc1[2], acc1[3]);
  float lmin =  3.4e38f, lmax = -3.4e38f;
  #pragma unroll
  for (int r = 0; r < 4; r++){
    lmin = fminf(lmin, fminf(acc0[r], acc1[r]));
    lmax = fmaxf(lmax, fmaxf(acc0[r], acc1[r]));
  }
  #pragma unroll
  for (int d = 32; d >= 1; d >>= 1){
    lmin = fminf(lmin, __shfl_xor(lmin, d, 64));
    lmax = fmaxf(lmax, __shfl_xor(lmax, d, 64));
  }
  if (lane == 0){ sm[wave] = lmin; sm[8+wave] = lmax; }
  __syncthreads();
  if (tid == 0){
    wsf[16   + b] = fminf(fminf(sm[0], sm[1]), fminf(sm[2], sm[3]));
    wsf[1296 + b] = fmaxf(fmaxf(sm[8], sm[9]), fmaxf(sm[10], sm[11]));
  }
}

// one-block reduction: global min/max over 1280 block slots + sum of 5120 stds
// -> writes splat constants wsf[0..3], hscale wsf[8], then the tap table
// (76 float2 at wsf[16..168)) and corr table (wsf[168..424)), which are
// identical for every k_kde block.
__global__ __launch_bounds__(1024) void k_red(float* __restrict__ wsf,
                                              float divisor, float k2c){
  __shared__ float rmn[1024], rmx[1024], rs[1024];
  int tid = threadIdx.x;
  float mn = 3.4e38f, mx = -3.4e38f, s = 0.f;
  for (int i = tid; i < 1280; i += 1024){
    mn = fminf(mn, wsf[16   + i]);
    mx = fmaxf(mx, wsf[1296 + i]);
  }
  for (int i = tid; i < 5120; i += 1024){
    float a  = wsf[2576 + i];
    float a2 = wsf[7696 + i];
    float mean = a * (1.0f/512.0f);
    float var  = a2 * (1.0f/512.0f) - mean*mean;
    s += sqrtf(fmaxf(var, 0.0f));
  }
  rmn[tid] = mn; rmx[tid] = mx; rs[tid] = s;
  __syncthreads();
  for (int g = 512; g >= 1; g >>= 1){
    if (tid < g){
      rmn[tid] = fminf(rmn[tid], rmn[tid+g]);
      rmx[tid] = fmaxf(rmx[tid], rmx[tid+g]);
      rs[tid] += rs[tid+g];
    }
    __syncthreads();
  }
  // all threads recompute the constants identically from the reduced values
  float rstd   = 5120.0f / rs[0];
  float leftS  = rmn[0] * rstd;
  float rightS = rmx[0] * rstd;
  float stepFS = (rightS - leftS) * (1.0f/999.0f);
  if (tid == 0){
    float inv2 = 1.0f / (2.0f * stepFS);
    wsf[0] = rstd * inv2;    // posScale
    wsf[1] = leftS * inv2;   // posOff
    wsf[2] = stepFS;
    wsf[3] = leftS;
    wsf[8] = ((rightS - leftS) * (1.0f/1000.0f)) * 0.5f / divisor;  // hscale
  }
  float sh = 2.0f * stepFS;
  // tap table sK2 (flat floats): sK2[0..7]=0 (pair pad), pair p at [8+2p..]
  if (tid < 152){
    float v = 0.f;
    if (tid >= 8){
      int pr = (tid >> 1) - 4;       // pair index 0..71
      int u  = pr - 34;
      float d = (tid & 1) ? (float)(2*u-1) * sh : (float)(2*u) * sh;
      v = (pr < 69) ? fexp2(k2c*d*d) : 0.f;
    }
    wsf[16 + tid] = v;
  }
  if (tid >= 256 && tid < 512){
    int idx = tid - 256;
    float xc = fmaf((float)(idx - 1), 4.0f*stepFS, leftS);
    wsf[168 + idx] = fexp2(k2c * xc * xc);
  }
}

// KDE: 256 threads, wave = env. Padded histogram (2-word pad per 8 words:
// W(w) = w + ((w>>3)<<1)) keeps float2 reads aligned AND makes the FIR's
// 8-word lane stride conflict-free (10-word effective stride = exactly
// 4 word-accesses/bank). Each lane computes 4 CONSECUTIVE FIR outputs with a
// sliding coefficient-register rotation: 1 H-load + 1 uniform tap-load per
// iteration (was 4+1 for the same outputs). Tables are preloaded from k_red.
// smem: p[0..2048) (st reuses [0..1024)) | hist 4x824 [2048..5344) |
//       taps [5344..5496) | corr [5496..5752) | partials [5752..5776)
__global__ __launch_bounds__(256) void k_kde(const float* __restrict__ projT,
                      const int* __restrict__ dlen, const float* __restrict__ wsf,
                      float* __restrict__ dpair){
  __shared__ __align__(16) float smem[5776];
  int b = blockIdx.x;          // 0..1279
  int l = b >> 7, f = b & 127;
  int tid = threadIdx.x, wave = tid >> 6, lane = tid & 63;
  int e = wave;
  // stage p UNSCALED (rstd folded into splat constants): 2 float4 per thread
  {
    int e0 = tid >> 7, mq = tid & 127;
    ((float4*)smem)[tid] =
      ((const float4*)(projT + (((size_t)e0 * L_ + l) * F_ + f) * M_))[mq];
    ((float4*)smem)[tid + 256] =
      ((const float4*)(projT + (((size_t)(e0+2) * L_ + l) * F_ + f) * M_))[mq];
  }
  float posScale = wsf[0], posOff = wsf[1];
  // zero padded hist (824 floats per env, 4 envs = 824 float4s total)
  for (int idx = tid; idx < 824; idx += 256)
    ((float4*)(smem + 2048))[idx] = make_float4(0.f,0.f,0.f,0.f);
  // preload tables (identical across blocks, computed once in k_red)
  if (tid < 38)
    ((float4*)(smem + 5344))[tid] = ((const float4*)(wsf + 16))[tid];
  if (tid >= 64 && tid < 128)
    ((float4*)(smem + 5496))[tid - 64] = ((const float4*)(wsf + 168))[tid - 64];
  __syncthreads();   // #1: p staged, hist zeroed, tables loaded
  // quadratic (TSC) splat into padded histogram; wave e owns env e
  {
    float* hf = smem + 2048 + e*824;
    const float4* spw4 = (const float4*)(smem + e*512);
    float4 p0 = spw4[lane], p1 = spw4[lane + 64];
    float pv[8] = {p0.x,p0.y,p0.z,p0.w,p1.x,p1.y,p1.z,p1.w};
    #pragma unroll
    for (int i = 0; i < 8; i++){
      float pos = fmaf(pv[i], posScale, -posOff);
      float n = floorf(pos + 0.5f);
      float d = pos - n;
      float wm = 0.5f*(0.5f-d)*(0.5f-d);
      float wp = 0.5f*(0.5f+d)*(0.5f+d);
      float w0 = 0.75f - d*d;
      int b0 = (int)n + 71;
      int b1 = b0 + 1, b2 = b0 + 2;
      int W0 = b0 + ((b0>>3)<<1);
      int W1 = b1 + ((b1>>3)<<1);
      int W2 = b2 + ((b2>>3)<<1);
      atomicAdd(&hf[W0], wm);
      atomicAdd(&hf[W1], w0);
      atomicAdd(&hf[W2], wp);
    }
  }
  __syncthreads();   // #2: histograms complete, p reads done
  // FIR: lane computes 4 consecutive outputs o = 4*lane + r of env e.
  // out(o0+r) = sum_{i=1..72} sK2[73-i+r] . H(i),  H(i) = hist float2 at
  // word 2i+2*o0 (padded address). Coefficients rotate through c0..c3.
  float lenE = (float)dlen[e*L_ + l];
  float rlen = 1.0f / lenE;
  float padc = 512.0f - lenE;
  {
    const float2* sK2 = (const float2*)(smem + 5344);
    const float* hb = smem + 2048 + e*824;
    int wb = 8*lane;
    float2 c0 = sK2[72], c1 = sK2[73], c2 = sK2[74], c3 = sK2[75];
    float a0=0.f, a1=0.f, a2=0.f, a3=0.f;
    #pragma unroll 8
    for (int i = 1; i <= 72; i++){
      int w  = wb + 2*i;
      int wp_ = w + ((w>>3)<<1);
      float2 H = *(const float2*)&hb[wp_];
      a0 = fmaf(H.x, c0.x, fmaf(H.y, c0.y, a0));
      a1 = fmaf(H.x, c1.x, fmaf(H.y, c1.y, a1));
      a2 = fmaf(H.x, c2.x, fmaf(H.y, c2.y, a2));
      a3 = fmaf(H.x, c3.x, fmaf(H.y, c3.y, a3));
      c3 = c2; c2 = c1; c1 = c0; c0 = sK2[72 - i];
    }
    int o0 = 4*lane;
    float4 cr = *(const float4*)&smem[5496 + o0];
    float4 stv = make_float4((a0 - padc*cr.x)*rlen, (a1 - padc*cr.y)*rlen,
                             (a2 - padc*cr.z)*rlen, (a3 - padc*cr.w)*rlen);
    *(float4*)&smem[e*256 + o0] = stv;
  }
  __syncthreads();   // #3: st complete for all envs
  // fine grid: thread tid handles t = 4*tid..4*tid+3 (all share cc = tid).
  // Lagrange weights for u = k*0.25 constant-fold to the same IEEE values the
  // runtime expressions produced.
  float ps[6] = {0,0,0,0,0,0};
  if (tid < 250){
    float x[4][4];
    #pragma unroll
    for (int ee=0; ee<4; ee++){
      const float* st = &smem[ee*256 + tid];
      x[ee][0]=st[0]; x[ee][1]=st[1]; x[ee][2]=st[2]; x[ee][3]=st[3];
    }
    #pragma unroll
    for (int k=0; k<4; k++){
      float u = (float)k * 0.25f;
      float um1 = u - 1.0f, um2 = u - 2.0f, up1 = u + 1.0f;
      float w0 = -u * um1 * um2 * (1.0f/6.0f);
      float w1 = up1 * um1 * um2 * 0.5f;
      float w2 = -u * up1 * um2 * 0.5f;
      float w3 = u * up1 * um1 * (1.0f/6.0f);
      float rr[4];
      #pragma unroll
      for (int ee=0; ee<4; ee++)
        rr[ee] = w0*x[ee][0] + w1*x[ee][1] + w2*x[ee][2] + w3*x[ee][3];
      ps[0] += fabsf(rr[0]-rr[1]);
      ps[1] += fabsf(rr[0]-rr[2]);
      ps[2] += fabsf(rr[0]-rr[3]);
      ps[3] += fabsf(rr[1]-rr[2]);
      ps[4] += fabsf(rr[1]-rr[3]);
      ps[5] += fabsf(rr[2]-rr[3]);
    }
  }
  #pragma unroll
  for (int pr=0; pr<6; pr++){
    float v = ps[pr];
    #pragma unroll
    for (int d=32; d>=1; d>>=1) v += __shfl_xor(v, d, 64);
    if (lane == 0) smem[5752 + wave*6 + pr] = v;
  }
  __syncthreads();   // #4: partials visible
  if (tid < 6)
    dpair[tid*1280 + b] = smem[5752+tid] + smem[5758+tid] + smem[5764+tid] + smem[5770+tid];
}

// finalize: scale, masked max over pairs, then max over L + mean over F
__global__ void k_fin(const float* __restrict__ dpair, const float* __restrict__ wsf,
                      const int* __restrict__ istrain, float* __restrict__ out){
  __shared__ float str[1280], ste[1280];
  __shared__ float s1[128], s2[128];
  int tid = threadIdx.x;   // 256 threads, 1 block
  float hscale = wsf[8];
  bool t0 = istrain[0]!=0, t1 = istrain[1]!=0, t2 = istrain[2]!=0, t3 = istrain[3]!=0;
  bool trn[6] = { t0&&t1, t0&&t2, t0&&t3, t1&&t2, t1&&t3, t2&&t3 };
  for (int idx = tid; idx < 1280; idx += 256){
    float tmax = -INFINITY, trmax = -INFINITY;
    #pragma unroll
    for (int pr=0;pr<6;pr++){
      float h = dpair[pr*1280 + idx] * hscale;
      tmax = fmaxf(tmax, h);
      if (trn[pr]) trmax = fmaxf(trmax, h);
    }
    out[idx]        = trmax;   // train_results
    out[1280 + idx] = tmax;    // test_results
    str[idx] = trmax; ste[idx] = tmax;
  }
  __syncthreads();
  if (tid < 128){
    float m1 = -INFINITY, m2 = -INFINITY;
    for (int l=0;l<L_;l++){
      m1 = fmaxf(m1, str[l*F_ + tid]);
      m2 = fmaxf(m2, ste[l*F_ + tid]);
    }
    s1[tid] = m1; s2[tid] = m2;
  }
  __syncthreads();
  for (int g=64; g>=1; g>>=1){
    if (tid < g){ s1[tid] += s1[tid+g]; s2[tid] += s2[tid+g]; }
    __syncthreads();
  }
  if (tid == 0){
    out[2560] = s1[0] * (1.0f/128.0f);
    out[2561] = s2[0] * (1.0f/128.0f);
  }
}

extern "C" void kernel_launch(void* const* d_in, const int* in_sizes, int n_in,
                              void* d_out, int out_size, void* d_ws, size_t ws_size,
                              hipStream_t stream){
  const float* mat = (const float*)d_in[0];
  const float* par = (const float*)d_in[1];
  const int*  dlen = (const int*)d_in[2];
  const int*  istr = (const int*)d_in[3];
  float* out   = (float*)d_out;
  float* wsf   = (float*)d_ws;
  float* dpair = wsf + 12816;
  float* projT = wsf + 20496;

  // host-computable constants (bw's data-dependent factor is identically 1)
  double bw_d   = 1.06 * pow(512.0, -0.2);
  float  bw     = (float)bw_d;
  float  offset = expf(-0.5f / (bw*bw));
  float  k2c    = (float)(log((double)offset) * 1.4426950408889634);  // log2(offset)
  float  divisor = sqrtf(6.283185307179586f) * bw;

  k_pre <<<1320, 256, 0, stream>>>(mat, par, projT, wsf);
  k_red <<<1,   1024, 0, stream>>>(wsf, divisor, k2c);
  k_kde <<<1280, 256, 0, stream>>>(projT, dlen, wsf, dpair);
  k_fin <<<1,    256, 0, stream>>>(dpair, wsf, istr, out);
}

// Round 4
// 142.176 us; speedup vs baseline: 1.0835x; 1.0116x over previous
//
#include <hip/hip_runtime.h>
#include <cmath>

#define E_ 4
#define L_ 10
#define M_ 512
#define F_ 128
#define S_ 1000

typedef unsigned int u32;
typedef _Float16 f16;
typedef __attribute__((ext_vector_type(8))) _Float16 v8h;
typedef __attribute__((ext_vector_type(4))) float v4f;

__device__ __forceinline__ float fexp2(float a){
#if __has_builtin(__builtin_amdgcn_exp2f)
  return __builtin_amdgcn_exp2f(a);
#else
  return exp2f(a);
#endif
}

// ws float layout (total 282640 <= 288768 proven available):
// [0..4)         splat consts: posScale, posOff, stepFS, leftS (written by k_red)
// [8]            hscale (written by k_red, read by k_fin)
// [16..168)      tap table sK2: 76 float2 (zero-padded), written by k_red AFTER
//                the min/max slots are consumed (reuse of the min region)
// [168..424)     corr table [256], written by k_red (reuse of min region)
// [16..1296)     per-gemm-block min   (live only k_pre -> k_red)
// [1296..2576)   per-gemm-block max
// [2576..7696)   std S1 partials [40][128]
// [7696..12816)  std S2 partials [40][128]
// [12816..20496) dpair[6][1280]
// [20496..282640) projT[E][L][F][M] (unscaled, m contiguous)

// blocks 0..1279: MFMA f16 GEMM tile (direct global loads/stores) + block min/max
// blocks 1280..1319: per-(e,l) std partial sums (float4 loads, 8 parts x 64 iters)
__global__ __launch_bounds__(256) void k_pre(const float* __restrict__ mat,
                       const float* __restrict__ par,
                       float* __restrict__ projT, float* __restrict__ wsf){
  __shared__ float sm[2048];
  int b = blockIdx.x, tid = threadIdx.x;
  if (b >= 1280){
    int el = b - 1280;
    int fq = (tid & 31) * 4, part = tid >> 5;     // 8 parts x 64 samples
    const float* base = mat + ((size_t)el * M_ + part*64) * F_;
    float4 s  = make_float4(0.f,0.f,0.f,0.f);
    float4 s2 = make_float4(0.f,0.f,0.f,0.f);
    #pragma unroll 8
    for (int i = 0; i < 64; i++){
      float4 v = *(const float4*)&base[i*F_ + fq];
      s.x += v.x; s.y += v.y; s.z += v.z; s.w += v.w;
      s2.x += v.x*v.x; s2.y += v.y*v.y; s2.z += v.z*v.z; s2.w += v.w*v.w;
    }
    ((float4*)sm)[tid]       = s;
    ((float4*)sm)[256 + tid] = s2;
    __syncthreads();
    // tree-reduce the 8 parts
    for (int g = 4; g >= 1; g >>= 1){
      if (part < g){
        float4 o  = ((float4*)sm)[tid + g*32];
        float4 o2 = ((float4*)sm)[256 + tid + g*32];
        s.x += o.x; s.y += o.y; s.z += o.z; s.w += o.w;
        s2.x += o2.x; s2.y += o2.y; s2.z += o2.z; s2.w += o2.w;
        ((float4*)sm)[tid] = s;
        ((float4*)sm)[256 + tid] = s2;
      }
      __syncthreads();
    }
    if (part == 0){
      *(float4*)&wsf[2576 + el*128 + fq] = s;
      *(float4*)&wsf[7696 + el*128 + fq] = s2;
    }
    return;
  }
  int el = b >> 5, mt = (b & 31) * 16;
  int lane = tid & 63, wave = tid >> 6;
  int q = (lane >> 4) & 3, m16 = lane & 15;
  const float* arow = mat + ((size_t)el * M_ + mt + m16) * F_;
  v4f acc0 = {0.f,0.f,0.f,0.f}, acc1 = {0.f,0.f,0.f,0.f};
  #pragma unroll
  for (int c = 0; c < 4; c++){
    float4 a0 = *(const float4*)&arow[c*32 + q*8];
    float4 a1 = *(const float4*)&arow[c*32 + q*8 + 4];
    v8h af, b0, b1;
    af[0]=(f16)a0.x; af[1]=(f16)a0.y; af[2]=(f16)a0.z; af[3]=(f16)a0.w;
    af[4]=(f16)a1.x; af[5]=(f16)a1.y; af[6]=(f16)a1.z; af[7]=(f16)a1.w;
    const float* pb = par + (c*32 + q*8)*F_ + wave*32 + m16;
    #pragma unroll
    for (int j = 0; j < 8; j++){
      b0[j] = (f16)pb[j*F_];
      b1[j] = (f16)pb[j*F_ + 16];
    }
    acc0 = __builtin_amdgcn_mfma_f32_16x16x32_f16(af, b0, acc0, 0, 0, 0);
    acc1 = __builtin_amdgcn_mfma_f32_16x16x32_f16(af, b1, acc1, 0, 0, 0);
  }
  // direct stores: C/D row=q*4+r (m), col=m16 (n) -> projT[el][n][m]
  *(float4*)(projT + ((size_t)el*F_ + wave*32      + m16)*M_ + mt + q*4)
      = make_float4(acc0[0], acc0[1], acc0[2], acc0[3]);
  *(float4*)(projT + ((size_t)el*F_ + wave*32 + 16 + m16)*M_ + mt + q*4)
      = make_float4(acc1[0], acc1[1], acc1[2], acc1[3]);
  float lmin =  3.4e38f, lmax = -3.4e38f;
  #pragma unroll
  for (int r = 0; r < 4; r++){
    lmin = fminf(lmin, fminf(acc0[r], acc1[r]));
    lmax = fmaxf(lmax, fmaxf(acc0[r], acc1[r]));
  }
  #pragma unroll
  for (int d = 32; d >= 1; d >>= 1){
    lmin = fminf(lmin, __shfl_xor(lmin, d, 64));
    lmax = fmaxf(lmax, __shfl_xor(lmax, d, 64));
  }
  if (lane == 0){ sm[wave] = lmin; sm[8+wave] = lmax; }
  __syncthreads();
  if (tid == 0){
    wsf[16   + b] = fminf(fminf(sm[0], sm[1]), fminf(sm[2], sm[3]));
    wsf[1296 + b] = fmaxf(fmaxf(sm[8], sm[9]), fmaxf(sm[10], sm[11]));
  }
}

// one-block reduction: global min/max over 1280 block slots + sum of 5120 stds
// -> writes splat constants wsf[0..3], hscale wsf[8], then the tap table
// (76 float2 at wsf[16..168)) and corr table (wsf[168..424)), which are
// identical for every k_kde block.
__global__ __launch_bounds__(1024) void k_red(float* __restrict__ wsf,
                                              float divisor, float k2c){
  __shared__ float rmn[1024], rmx[1024], rs[1024];
  int tid = threadIdx.x;
  float mn = 3.4e38f, mx = -3.4e38f, s = 0.f;
  for (int i = tid; i < 1280; i += 1024){
    mn = fminf(mn, wsf[16   + i]);
    mx = fmaxf(mx, wsf[1296 + i]);
  }
  for (int i = tid; i < 5120; i += 1024){
    float a  = wsf[2576 + i];
    float a2 = wsf[7696 + i];
    float mean = a * (1.0f/512.0f);
    float var  = a2 * (1.0f/512.0f) - mean*mean;
    s += sqrtf(fmaxf(var, 0.0f));
  }
  rmn[tid] = mn; rmx[tid] = mx; rs[tid] = s;
  __syncthreads();
  for (int g = 512; g >= 1; g >>= 1){
    if (tid < g){
      rmn[tid] = fminf(rmn[tid], rmn[tid+g]);
      rmx[tid] = fmaxf(rmx[tid], rmx[tid+g]);
      rs[tid] += rs[tid+g];
    }
    __syncthreads();
  }
  // all threads recompute the constants identically from the reduced values
  float rstd   = 5120.0f / rs[0];
  float leftS  = rmn[0] * rstd;
  float rightS = rmx[0] * rstd;
  float stepFS = (rightS - leftS) * (1.0f/999.0f);
  if (tid == 0){
    float inv2 = 1.0f / (2.0f * stepFS);
    wsf[0] = rstd * inv2;    // posScale
    wsf[1] = leftS * inv2;   // posOff
    wsf[2] = stepFS;
    wsf[3] = leftS;
    wsf[8] = ((rightS - leftS) * (1.0f/1000.0f)) * 0.5f / divisor;  // hscale
  }
  float sh = 2.0f * stepFS;
  // tap table sK2 (flat floats): sK2[0..7]=0 (pair pad), pair p at [8+2p..]
  if (tid < 152){
    float v = 0.f;
    if (tid >= 8){
      int pr = (tid >> 1) - 4;       // pair index 0..71
      int u  = pr - 34;
      float d = (tid & 1) ? (float)(2*u-1) * sh : (float)(2*u) * sh;
      v = (pr < 69) ? fexp2(k2c*d*d) : 0.f;
    }
    wsf[16 + tid] = v;
  }
  if (tid >= 256 && tid < 512){
    int idx = tid - 256;
    float xc = fmaf((float)(idx - 1), 4.0f*stepFS, leftS);
    wsf[168 + idx] = fexp2(k2c * xc * xc);
  }
}

// KDE: 256 threads, wave = env. No p staging (splat reads projT directly,
// coalesced per-wave; loads issued before barrier #1 so they fly under the
// hist-zero/table phase). Padded histogram (W(w)=w+((w>>3)<<1)) keeps float2
// reads aligned and conflict-free. FIR fully unrolled: padded address =
// 10*lane + (2i + 2*(i>>2)) = per-lane base + compile-time immediate offset;
// coefficient rotation becomes register renaming (zero movs, zero addr VALU).
// smem: st [0..1024) | hist 4x824 [1024..4320) | taps [4320..4472) |
//       corr [4472..4728) | partials [4728..4752)
__global__ __launch_bounds__(256) void k_kde(const float* __restrict__ projT,
                      const int* __restrict__ dlen, const float* __restrict__ wsf,
                      float* __restrict__ dpair){
  __shared__ __align__(16) float smem[4752];
  int b = blockIdx.x;          // 0..1279
  int l = b >> 7, f = b & 127;
  int tid = threadIdx.x, wave = tid >> 6, lane = tid & 63;
  int e = wave;
  // issue the splat source loads NOW (consumed after barrier #1)
  const float4* gp = (const float4*)(projT + (((size_t)e * L_ + l) * F_ + f) * M_);
  float4 g0 = gp[lane], g1 = gp[lane + 64];
  float posScale = wsf[0], posOff = wsf[1];
  // zero padded hist (824 floats per env, 4 envs = 824 float4s total)
  for (int idx = tid; idx < 824; idx += 256)
    ((float4*)(smem + 1024))[idx] = make_float4(0.f,0.f,0.f,0.f);
  // preload tables (identical across blocks, computed once in k_red)
  if (tid < 38)
    ((float4*)(smem + 4320))[tid] = ((const float4*)(wsf + 16))[tid];
  if (tid >= 64 && tid < 128)
    ((float4*)(smem + 4472))[tid - 64] = ((const float4*)(wsf + 168))[tid - 64];
  __syncthreads();   // #1: hist zeroed, tables loaded
  // quadratic (TSC) splat into padded histogram; wave e owns env e
  {
    float* hf = smem + 1024 + e*824;
    float pv[8] = {g0.x,g0.y,g0.z,g0.w,g1.x,g1.y,g1.z,g1.w};
    #pragma unroll
    for (int i = 0; i < 8; i++){
      float pos = fmaf(pv[i], posScale, -posOff);
      float n = floorf(pos + 0.5f);
      float d = pos - n;
      float wm = 0.5f*(0.5f-d)*(0.5f-d);
      float wp = 0.5f*(0.5f+d)*(0.5f+d);
      float w0 = 0.75f - d*d;
      int b0 = (int)n + 71;
      int b1 = b0 + 1, b2 = b0 + 2;
      int W0 = b0 + ((b0>>3)<<1);
      int W1 = b1 + ((b1>>3)<<1);
      int W2 = b2 + ((b2>>3)<<1);
      atomicAdd(&hf[W0], wm);
      atomicAdd(&hf[W1], w0);
      atomicAdd(&hf[W2], wp);
    }
  }
  __syncthreads();   // #2: histograms complete
  // FIR: lane computes 4 consecutive outputs o = 4*lane + r of env e.
  // Fully unrolled; H loads are ds_read_b64 at immediate offsets from a
  // per-lane base (10*lane floats); taps rotate through renamed registers.
  float lenE = (float)dlen[e*L_ + l];
  float rlen = 1.0f / lenE;
  float padc = 512.0f - lenE;
  {
    const float2* sK2 = (const float2*)(smem + 4320);
    const float* hl = smem + 1024 + e*824 + 10*lane;
    float2 c0 = sK2[72], c1 = sK2[73], c2 = sK2[74], c3 = sK2[75];
    float a0=0.f, a1=0.f, a2=0.f, a3=0.f;
    #pragma unroll
    for (int i = 1; i <= 72; i++){
      float2 H = *(const float2*)&hl[2*i + 2*(i>>2)];
      a0 = fmaf(H.x, c0.x, fmaf(H.y, c0.y, a0));
      a1 = fmaf(H.x, c1.x, fmaf(H.y, c1.y, a1));
      a2 = fmaf(H.x, c2.x, fmaf(H.y, c2.y, a2));
      a3 = fmaf(H.x, c3.x, fmaf(H.y, c3.y, a3));
      c3 = c2; c2 = c1; c1 = c0; c0 = sK2[72 - i];
    }
    int o0 = 4*lane;
    float4 cr = *(const float4*)&smem[4472 + o0];
    float4 stv = make_float4((a0 - padc*cr.x)*rlen, (a1 - padc*cr.y)*rlen,
                             (a2 - padc*cr.z)*rlen, (a3 - padc*cr.w)*rlen);
    *(float4*)&smem[e*256 + o0] = stv;
  }
  __syncthreads();   // #3: st complete for all envs
  // fine grid: thread tid handles t = 4*tid..4*tid+3 (all share cc = tid).
  // Lagrange weights for u = k*0.25 constant-fold to the same IEEE values the
  // runtime expressions produced.
  float ps[6] = {0,0,0,0,0,0};
  if (tid < 250){
    float x[4][4];
    #pragma unroll
    for (int ee=0; ee<4; ee++){
      const float* st = &smem[ee*256 + tid];
      x[ee][0]=st[0]; x[ee][1]=st[1]; x[ee][2]=st[2]; x[ee][3]=st[3];
    }
    #pragma unroll
    for (int k=0; k<4; k++){
      float u = (float)k * 0.25f;
      float um1 = u - 1.0f, um2 = u - 2.0f, up1 = u + 1.0f;
      float w0 = -u * um1 * um2 * (1.0f/6.0f);
      float w1 = up1 * um1 * um2 * 0.5f;
      float w2 = -u * up1 * um2 * 0.5f;
      float w3 = u * up1 * um1 * (1.0f/6.0f);
      float rr[4];
      #pragma unroll
      for (int ee=0; ee<4; ee++)
        rr[ee] = w0*x[ee][0] + w1*x[ee][1] + w2*x[ee][2] + w3*x[ee][3];
      ps[0] += fabsf(rr[0]-rr[1]);
      ps[1] += fabsf(rr[0]-rr[2]);
      ps[2] += fabsf(rr[0]-rr[3]);
      ps[3] += fabsf(rr[1]-rr[2]);
      ps[4] += fabsf(rr[1]-rr[3]);
      ps[5] += fabsf(rr[2]-rr[3]);
    }
  }
  #pragma unroll
  for (int pr=0; pr<6; pr++){
    float v = ps[pr];
    #pragma unroll
    for (int d=32; d>=1; d>>=1) v += __shfl_xor(v, d, 64);
    if (lane == 0) smem[4728 + wave*6 + pr] = v;
  }
  __syncthreads();   // #4: partials visible
  if (tid < 6)
    dpair[tid*1280 + b] = smem[4728+tid] + smem[4734+tid] + smem[4740+tid] + smem[4746+tid];
}

// finalize: scale, masked max over pairs, then max over L + mean over F
__global__ void k_fin(const float* __restrict__ dpair, const float* __restrict__ wsf,
                      const int* __restrict__ istrain, float* __restrict__ out){
  __shared__ float str[1280], ste[1280];
  __shared__ float s1[128], s2[128];
  int tid = threadIdx.x;   // 256 threads, 1 block
  float hscale = wsf[8];
  bool t0 = istrain[0]!=0, t1 = istrain[1]!=0, t2 = istrain[2]!=0, t3 = istrain[3]!=0;
  bool trn[6] = { t0&&t1, t0&&t2, t0&&t3, t1&&t2, t1&&t3, t2&&t3 };
  for (int idx = tid; idx < 1280; idx += 256){
    float tmax = -INFINITY, trmax = -INFINITY;
    #pragma unroll
    for (int pr=0;pr<6;pr++){
      float h = dpair[pr*1280 + idx] * hscale;
      tmax = fmaxf(tmax, h);
      if (trn[pr]) trmax = fmaxf(trmax, h);
    }
    out[idx]        = trmax;   // train_results
    out[1280 + idx] = tmax;    // test_results
    str[idx] = trmax; ste[idx] = tmax;
  }
  __syncthreads();
  if (tid < 128){
    float m1 = -INFINITY, m2 = -INFINITY;
    for (int l=0;l<L_;l++){
      m1 = fmaxf(m1, str[l*F_ + tid]);
      m2 = fmaxf(m2, ste[l*F_ + tid]);
    }
    s1[tid] = m1; s2[tid] = m2;
  }
  __syncthreads();
  for (int g=64; g>=1; g>>=1){
    if (tid < g){ s1[tid] += s1[tid+g]; s2[tid] += s2[tid+g]; }
    __syncthreads();
  }
  if (tid == 0){
    out[2560] = s1[0] * (1.0f/128.0f);
    out[2561] = s2[0] * (1.0f/128.0f);
  }
}

extern "C" void kernel_launch(void* const* d_in, const int* in_sizes, int n_in,
                              void* d_out, int out_size, void* d_ws, size_t ws_size,
                              hipStream_t stream){
  const float* mat = (const float*)d_in[0];
  const float* par = (const float*)d_in[1];
  const int*  dlen = (const int*)d_in[2];
  const int*  istr = (const int*)d_in[3];
  float* out   = (float*)d_out;
  float* wsf   = (float*)d_ws;
  float* dpair = wsf + 12816;
  float* projT = wsf + 20496;

  // host-computable constants (bw's data-dependent factor is identically 1)
  double bw_d   = 1.06 * pow(512.0, -0.2);
  float  bw     = (float)bw_d;
  float  offset = expf(-0.5f / (bw*bw));
  float  k2c    = (float)(log((double)offset) * 1.4426950408889634);  // log2(offset)
  float  divisor = sqrtf(6.283185307179586f) * bw;

  k_pre <<<1320, 256, 0, stream>>>(mat, par, projT, wsf);
  k_red <<<1,   1024, 0, stream>>>(wsf, divisor, k2c);
  k_kde <<<1280, 256, 0, stream>>>(projT, dlen, wsf, dpair);
  k_fin <<<1,    256, 0, stream>>>(dpair, wsf, istr, out);
}